// Round 3
// baseline (6980.055 us; speedup 1.0000x reference)
//
#include <hip/hip_runtime.h>
#include <hip/hip_bf16.h>
#include <stdint.h>

#define T_STEPS 512
#define BATCH   64
#define DIN     512
#define DLAT    1024
#define NWG     256          // 128 col-groups x 2 row-halves = all 256 CUs

typedef __bf16 bf16_t;
typedef __bf16 bf16x4 __attribute__((ext_vector_type(4)));
typedef __bf16 bf16x8 __attribute__((ext_vector_type(8)));
typedef float  f32x4  __attribute__((ext_vector_type(4)));

// ---- workspace layout (bytes) ----
#define XB_OFF    0u                        // bf16 x [512][64][512] = 33,554,432
#define HRING_OFF 33554432u                 // bf16 h ring [2][64][1024] = 262,144
#define CNT_OFF   (HRING_OFF + 262144u)     // int cnt[512] = 2,048
#define ZERO_BYTES (262144u + 2048u)

// LDS: partials f32 [4 waves][32 cols][36 rows-padded] = 18,432 bytes used.
// Request 96 KB to force 1 WG/CU (even spread over all 256 CUs).
#define LDS_BYTES 98304

__global__ void xconv_kernel(const float* __restrict__ x, bf16_t* __restrict__ xb) {
    size_t i = ((size_t)blockIdx.x * 256 + threadIdx.x) * 4;
    const float4 v = *(const float4*)(x + i);
    bf16x4 o;
    o[0] = (bf16_t)v.x; o[1] = (bf16_t)v.y; o[2] = (bf16_t)v.z; o[3] = (bf16_t)v.w;
    *(bf16x4*)(xb + i) = o;
}

__device__ __forceinline__ float sigmoidf_(float v) { return 1.f / (1.f + __expf(-v)); }

__launch_bounds__(256, 1)
__global__ void lstm_main(const float* __restrict__ Wf, const float* __restrict__ Wi,
                          const float* __restrict__ Wo, const float* __restrict__ Wu,
                          const float* __restrict__ bfp, const float* __restrict__ bip,
                          const float* __restrict__ bop, const float* __restrict__ bup,
                          const bf16_t* __restrict__ xb,
                          bf16_t* __restrict__ hring,
                          int* __restrict__ cnt,
                          float* __restrict__ out) {
    extern __shared__ char ldsraw[];
    float* part = (float*)ldsraw;   // [4][32 cols][36 rows]: idx = (w*32+col)*36 + row

    const int tid  = threadIdx.x;
    const int wv   = tid >> 6;       // wave 0..3 = K-slice
    const int lane = tid & 63;
    const int lm   = lane & 15;
    const int lq   = lane >> 4;
    const int cg   = blockIdx.x >> 1;   // col-group 0..127 -> j cols [cg*8, cg*8+8)
    const int rh   = blockIdx.x & 1;    // row half
    const int j0   = cg * 8;
    const int row0 = rh * 32;

    // ---- one-time: weights -> registers (24 bf16x8 = 96 VGPR) ----
    // Bfrag[fi][cf]: lane holds W[k = ksb + lq*8 + e][col = cf*16+lm], col = gate*8+jj
    bf16x8 Bfrag[12][2];
    {
        const float* Wgs[4] = {Wf, Wi, Wo, Wu};
#pragma unroll
        for (int fi = 0; fi < 12; ++fi) {
            const int ksb = (fi < 4) ? (wv * 128 + fi * 32)
                                     : (512 + wv * 256 + (fi - 4) * 32);
#pragma unroll
            for (int cf = 0; cf < 2; ++cf) {
                const int col = cf * 16 + lm;
                const int g = col >> 3, jj = col & 7;
                const float* wp = Wgs[g] + (size_t)(ksb + lq * 8) * DLAT + (j0 + jj);
                bf16x8 v;
#pragma unroll
                for (int e = 0; e < 8; ++e) v[e] = (bf16_t)wp[(size_t)e * DLAT];
                Bfrag[fi][cf] = v;
            }
        }
    }

    // elementwise ownership: one (row, j) per thread
    const int row_l = tid >> 3;          // 0..31 (local row)
    const int jp    = tid & 7;           // 0..7  (j within group)
    const float bias_r[4] = { bfp[j0 + jp], bip[j0 + jp], bop[j0 + jp], bup[j0 + jp] };
    float cst = 0.f;

    f32x4 acc[2][2];
#pragma unroll
    for (int rf = 0; rf < 2; ++rf)
#pragma unroll
        for (int cf = 0; cf < 2; ++cf) acc[rf][cf] = (f32x4){0.f, 0.f, 0.f, 0.f};

    // ---- prologue: x_0 GEMM (K-slice wv*128..+128) ----
#pragma unroll
    for (int ks = 0; ks < 4; ++ks) {
        const bf16x8 a0 = *(const bf16x8*)(xb + (size_t)(row0 + lm) * DIN + wv * 128 + ks * 32 + lq * 8);
        const bf16x8 a1 = *(const bf16x8*)(xb + (size_t)(row0 + 16 + lm) * DIN + wv * 128 + ks * 32 + lq * 8);
        acc[0][0] = __builtin_amdgcn_mfma_f32_16x16x32_bf16(a0, Bfrag[ks][0], acc[0][0], 0, 0, 0);
        acc[0][1] = __builtin_amdgcn_mfma_f32_16x16x32_bf16(a0, Bfrag[ks][1], acc[0][1], 0, 0, 0);
        acc[1][0] = __builtin_amdgcn_mfma_f32_16x16x32_bf16(a1, Bfrag[ks][0], acc[1][0], 0, 0, 0);
        acc[1][1] = __builtin_amdgcn_mfma_f32_16x16x32_bf16(a1, Bfrag[ks][1], acc[1][1], 0, 0, 0);
    }

    for (int t = 0; t < T_STEPS; ++t) {
        const bf16_t* hprev = hring + (size_t)(t & 1) * (BATCH * DLAT);
        bf16_t*       hnext = hring + (size_t)((t + 1) & 1) * (BATCH * DLAT);

        // ---- wait for h_{t-1} ----
        if (t > 0) {
            if (tid == 0) {
                while (__hip_atomic_load(&cnt[t - 1], __ATOMIC_RELAXED, __HIP_MEMORY_SCOPE_AGENT) < NWG)
                    __builtin_amdgcn_s_sleep(2);
            }
            __syncthreads();
            __builtin_amdgcn_fence(__ATOMIC_ACQUIRE, "agent");
        }

        // ---- h GEMM: wave K-slice [wv*256, wv*256+256), direct global->reg ----
#pragma unroll
        for (int ks = 0; ks < 8; ++ks) {
            const bf16x8 a0 = *(const bf16x8*)(hprev + (size_t)(row0 + lm) * DLAT + wv * 256 + ks * 32 + lq * 8);
            const bf16x8 a1 = *(const bf16x8*)(hprev + (size_t)(row0 + 16 + lm) * DLAT + wv * 256 + ks * 32 + lq * 8);
            acc[0][0] = __builtin_amdgcn_mfma_f32_16x16x32_bf16(a0, Bfrag[4 + ks][0], acc[0][0], 0, 0, 0);
            acc[0][1] = __builtin_amdgcn_mfma_f32_16x16x32_bf16(a0, Bfrag[4 + ks][1], acc[0][1], 0, 0, 0);
            acc[1][0] = __builtin_amdgcn_mfma_f32_16x16x32_bf16(a1, Bfrag[4 + ks][0], acc[1][0], 0, 0, 0);
            acc[1][1] = __builtin_amdgcn_mfma_f32_16x16x32_bf16(a1, Bfrag[4 + ks][1], acc[1][1], 0, 0, 0);
        }

        // ---- cross-wave K-reduction via LDS ----
        // acc[rf][cf][i] is (row = rf*16 + lq*4 + i, col = cf*16 + lm); store b128 per frag
#pragma unroll
        for (int rf = 0; rf < 2; ++rf)
#pragma unroll
            for (int cf = 0; cf < 2; ++cf) {
                const int col = cf * 16 + lm;
                *(f32x4*)&part[(wv * 32 + col) * 36 + rf * 16 + lq * 4] = acc[rf][cf];
            }
        __syncthreads();

        float gs[4];
#pragma unroll
        for (int g = 0; g < 4; ++g) {
            const int col = g * 8 + jp;
            gs[g] = part[(0 * 32 + col) * 36 + row_l] + part[(1 * 32 + col) * 36 + row_l]
                  + part[(2 * 32 + col) * 36 + row_l] + part[(3 * 32 + col) * 36 + row_l]
                  + bias_r[g];
        }
        const float ft = sigmoidf_(gs[0]);
        const float it = sigmoidf_(gs[1]);
        const float ot = sigmoidf_(gs[2]);
        const float ut = tanhf(gs[3]);
        cst = ft * cst + it * ut;
        const float hv = ot * tanhf(cst);

        out[(size_t)t * (BATCH * DLAT) + (size_t)(row0 + row_l) * DLAT + j0 + jp] = hv;

        // pack bf16 pair with neighbor lane, even lanes store 4B write-through
        const uint32_t hb = (uint32_t)__builtin_bit_cast(uint16_t, (bf16_t)hv);
        const uint32_t nb = __shfl_down(hb, 1);
        if ((lane & 1) == 0) {
            __hip_atomic_store((uint32_t*)(hnext + (size_t)(row0 + row_l) * DLAT + j0 + jp),
                               hb | (nb << 16), __ATOMIC_RELAXED, __HIP_MEMORY_SCOPE_AGENT);
        }
        asm volatile("s_waitcnt vmcnt(0)" ::: "memory");
        __syncthreads();                       // all threads' h/out stores drained
        if (tid == 0)
            __hip_atomic_fetch_add(&cnt[t], 1, __ATOMIC_RELAXED, __HIP_MEMORY_SCOPE_AGENT);

        // ---- prefetch x_{t+1} GEMM into fresh acc (hides the spin) ----
#pragma unroll
        for (int rf = 0; rf < 2; ++rf)
#pragma unroll
            for (int cf = 0; cf < 2; ++cf) acc[rf][cf] = (f32x4){0.f, 0.f, 0.f, 0.f};
        if (t + 1 < T_STEPS) {
            const bf16_t* xt = xb + (size_t)(t + 1) * (BATCH * DIN);
#pragma unroll
            for (int ks = 0; ks < 4; ++ks) {
                const bf16x8 a0 = *(const bf16x8*)(xt + (size_t)(row0 + lm) * DIN + wv * 128 + ks * 32 + lq * 8);
                const bf16x8 a1 = *(const bf16x8*)(xt + (size_t)(row0 + 16 + lm) * DIN + wv * 128 + ks * 32 + lq * 8);
                acc[0][0] = __builtin_amdgcn_mfma_f32_16x16x32_bf16(a0, Bfrag[ks][0], acc[0][0], 0, 0, 0);
                acc[0][1] = __builtin_amdgcn_mfma_f32_16x16x32_bf16(a0, Bfrag[ks][1], acc[0][1], 0, 0, 0);
                acc[1][0] = __builtin_amdgcn_mfma_f32_16x16x32_bf16(a1, Bfrag[ks][0], acc[1][0], 0, 0, 0);
                acc[1][1] = __builtin_amdgcn_mfma_f32_16x16x32_bf16(a1, Bfrag[ks][1], acc[1][1], 0, 0, 0);
            }
        }
    }
}

extern "C" void kernel_launch(void* const* d_in, const int* in_sizes, int n_in,
                              void* d_out, int out_size, void* d_ws, size_t ws_size,
                              hipStream_t stream) {
    const float* x  = (const float*)d_in[0];
    const float* Wf = (const float*)d_in[1];
    const float* Wi = (const float*)d_in[2];
    const float* Wo = (const float*)d_in[3];
    const float* Wu = (const float*)d_in[4];
    const float* bf = (const float*)d_in[5];
    const float* bi = (const float*)d_in[6];
    const float* bo = (const float*)d_in[7];
    const float* bu = (const float*)d_in[8];
    float* out = (float*)d_out;

    char* ws = (char*)d_ws;
    bf16_t* xb    = (bf16_t*)(ws + XB_OFF);
    bf16_t* hring = (bf16_t*)(ws + HRING_OFF);
    int*    cnt   = (int*)(ws + CNT_OFF);

    // zero h ring + step counters (every launch/replay)
    hipMemsetAsync(ws + HRING_OFF, 0, ZERO_BYTES, stream);

    // convert x -> bf16
    xconv_kernel<<<16384, 256, 0, stream>>>(x, xb);

    hipFuncSetAttribute((const void*)lstm_main,
                        hipFuncAttributeMaxDynamicSharedMemorySize, LDS_BYTES);

    lstm_main<<<NWG, 256, LDS_BYTES, stream>>>(Wf, Wi, Wo, Wu, bf, bi, bo, bu,
                                               xb, hring, cnt, out);
}

// Round 4
// 3317.517 us; speedup vs baseline: 2.1040x; 2.1040x over previous
//
#include <hip/hip_runtime.h>
#include <hip/hip_bf16.h>
#include <stdint.h>

#define T_STEPS 512
#define BATCH   64
#define DIN     512
#define DLAT    1024
#define NWG     256          // 128 col-groups x 2 row-halves = all 256 CUs

typedef __bf16 bf16_t;
typedef __bf16 bf16x4 __attribute__((ext_vector_type(4)));
typedef __bf16 bf16x8 __attribute__((ext_vector_type(8)));
typedef float  f32x4  __attribute__((ext_vector_type(4)));
typedef unsigned long long u64;
typedef u64 u64x2 __attribute__((ext_vector_type(2)));

// ---- workspace layout (bytes) ----
#define XB_OFF    0u                        // bf16 x [512][64][512] = 33,554,432
#define HRING_OFF 33554432u                 // bf16 h ring [2][64][1024] = 262,144
#define CNT_OFF   (HRING_OFF + 262144u)     // int cnt[512][8][16] = 262,144
#define ZERO_BYTES (262144u + 262144u)

// ---- LDS layout (bytes) ----
#define WT_OFF_B   0          // [32 cols][1536 k] bf16, XOR-swizzled = 98,304
#define PART_OFF_B 98304      // f32 [4][32][36] = 18,432
#define LDS_BYTES  116736     // forces 1 WG/CU

__global__ void xconv_kernel(const float* __restrict__ x, bf16_t* __restrict__ xb) {
    size_t i = ((size_t)blockIdx.x * 256 + threadIdx.x) * 4;
    const float4 v = *(const float4*)(x + i);
    bf16x4 o;
    o[0] = (bf16_t)v.x; o[1] = (bf16_t)v.y; o[2] = (bf16_t)v.z; o[3] = (bf16_t)v.w;
    *(bf16x4*)(xb + i) = o;
}

__device__ __forceinline__ float sigmoidf_(float v) { return 1.f / (1.f + __expf(-v)); }

// weight B-fragment from LDS (layout verified in R2): lane holds
// W[k = kabs + lq*8 + e][col], byte addr col*3072 + k*2 (^ (col&7)<<4)
__device__ __forceinline__ bf16x8 ldsB(const char* lds, int col, int kabs, int lq) {
    const uint32_t off = (uint32_t)(col * 3072 + kabs * 2 + lq * 16)
                       ^ (uint32_t)((col & 7) << 4);
    return *(const bf16x8*)(lds + WT_OFF_B + off);
}

// cache-bypassing (agent-scope) 16B load of h as bf16x8
__device__ __forceinline__ bf16x8 ldh(const bf16_t* p) {
    const u64* q = (const u64*)p;
    u64x2 t;
    t.x = __hip_atomic_load(q,     __ATOMIC_RELAXED, __HIP_MEMORY_SCOPE_AGENT);
    t.y = __hip_atomic_load(q + 1, __ATOMIC_RELAXED, __HIP_MEMORY_SCOPE_AGENT);
    return __builtin_bit_cast(bf16x8, t);
}

__launch_bounds__(256, 1)
__global__ void lstm_main(const float* __restrict__ Wf, const float* __restrict__ Wi,
                          const float* __restrict__ Wo, const float* __restrict__ Wu,
                          const float* __restrict__ bfp, const float* __restrict__ bip,
                          const float* __restrict__ bop, const float* __restrict__ bup,
                          const bf16_t* __restrict__ xb,
                          bf16_t* __restrict__ hring,
                          int* __restrict__ cnt,
                          float* __restrict__ out) {
    extern __shared__ char ldsraw[];
    float* part = (float*)(ldsraw + PART_OFF_B);   // [4][32 cols][36 rows]

    const int tid  = threadIdx.x;
    const int wv   = tid >> 6;       // wave 0..3 = K-slice
    const int lane = tid & 63;
    const int lm   = lane & 15;
    const int lq   = lane >> 4;
    const int cg   = blockIdx.x >> 1;   // col-group 0..127 -> j cols [cg*8, cg*8+8)
    const int rh   = blockIdx.x & 1;    // row half
    const int j0   = cg * 8;
    const int row0 = rh * 32;

    // ---- one-time: weights -> LDS bf16 [32 cols][1536 k], XOR-swizzled ----
    {
        const float* Wgs[4] = {Wf, Wi, Wo, Wu};
        const int gate = wv;            // wave = gate
        const int kr   = lane >> 1;     // 0..31
        const int jh   = lane & 1;      // 0/1: which float4 of the 8 cols
        const float* basep = Wgs[gate] + j0 + jh * 4;
        for (int i = 0; i < 48; ++i) {
            const int k = kr + i * 32;
            const float4 w4 = *(const float4*)(basep + (size_t)k * DLAT);
#pragma unroll
            for (int e = 0; e < 4; ++e) {
                const int c = gate * 8 + jh * 4 + e;
                const uint32_t a = (uint32_t)(c * 3072 + k * 2) ^ (uint32_t)((c & 7) << 4);
                *(bf16_t*)(ldsraw + WT_OFF_B + a) = (bf16_t)(&w4.x)[e];
            }
        }
    }

    // elementwise ownership: one (row, j) per thread
    const int row_l = tid >> 3;          // 0..31 (local row)
    const int jp    = tid & 7;           // 0..7  (j within group)
    const float bias_r[4] = { bfp[j0 + jp], bip[j0 + jp], bop[j0 + jp], bup[j0 + jp] };
    float cst = 0.f;

    __syncthreads();   // weights visible

    f32x4 acc[2][2];
#pragma unroll
    for (int rf = 0; rf < 2; ++rf)
#pragma unroll
        for (int cf = 0; cf < 2; ++cf) acc[rf][cf] = (f32x4){0.f, 0.f, 0.f, 0.f};

    // ---- prologue: x_0 GEMM (wave K-slice [wv*128, +128) of DIN) ----
#pragma unroll
    for (int ks = 0; ks < 4; ++ks) {
        const int kx = wv * 128 + ks * 32;
        const bf16x8 a0 = *(const bf16x8*)(xb + (size_t)(row0 + lm) * DIN + kx + lq * 8);
        const bf16x8 a1 = *(const bf16x8*)(xb + (size_t)(row0 + 16 + lm) * DIN + kx + lq * 8);
        const bf16x8 b0 = ldsB(ldsraw, lm,      kx, lq);
        const bf16x8 b1 = ldsB(ldsraw, 16 + lm, kx, lq);
        acc[0][0] = __builtin_amdgcn_mfma_f32_16x16x32_bf16(a0, b0, acc[0][0], 0, 0, 0);
        acc[0][1] = __builtin_amdgcn_mfma_f32_16x16x32_bf16(a0, b1, acc[0][1], 0, 0, 0);
        acc[1][0] = __builtin_amdgcn_mfma_f32_16x16x32_bf16(a1, b0, acc[1][0], 0, 0, 0);
        acc[1][1] = __builtin_amdgcn_mfma_f32_16x16x32_bf16(a1, b1, acc[1][1], 0, 0, 0);
    }

    for (int t = 0; t < T_STEPS; ++t) {
        const bf16_t* hprev = hring + (size_t)(t & 1) * (BATCH * DLAT);
        bf16_t*       hnext = hring + (size_t)((t + 1) & 1) * (BATCH * DLAT);

        // ---- wait for h_t (published as cnt[t-1]); no fence needed:
        // hring is only ever touched with cache-bypassing atomics ----
        if (t > 0) {
            if (tid == 0) {
                int* cb = cnt + (size_t)(t - 1) * 128;
                int s;
                do {
                    s = 0;
#pragma unroll
                    for (int i = 0; i < 8; ++i)
                        s += __hip_atomic_load(&cb[i * 16], __ATOMIC_RELAXED,
                                               __HIP_MEMORY_SCOPE_AGENT);
                    if (s < NWG) __builtin_amdgcn_s_sleep(1);
                } while (s < NWG);
            }
            __syncthreads();
        }

        // ---- h GEMM: wave K-slice [wv*256, +256) of DLAT, bypass loads ----
#pragma unroll
        for (int ks = 0; ks < 8; ++ks) {
            const int kh = wv * 256 + ks * 32;          // k within h
            const int kz = 512 + kh;                    // k within z (weights)
            const bf16x8 a0 = ldh(hprev + (size_t)(row0 + lm) * DLAT + kh + lq * 8);
            const bf16x8 a1 = ldh(hprev + (size_t)(row0 + 16 + lm) * DLAT + kh + lq * 8);
            const bf16x8 b0 = ldsB(ldsraw, lm,      kz, lq);
            const bf16x8 b1 = ldsB(ldsraw, 16 + lm, kz, lq);
            acc[0][0] = __builtin_amdgcn_mfma_f32_16x16x32_bf16(a0, b0, acc[0][0], 0, 0, 0);
            acc[0][1] = __builtin_amdgcn_mfma_f32_16x16x32_bf16(a0, b1, acc[0][1], 0, 0, 0);
            acc[1][0] = __builtin_amdgcn_mfma_f32_16x16x32_bf16(a1, b0, acc[1][0], 0, 0, 0);
            acc[1][1] = __builtin_amdgcn_mfma_f32_16x16x32_bf16(a1, b1, acc[1][1], 0, 0, 0);
        }

        // ---- cross-wave K-reduction via LDS ----
#pragma unroll
        for (int rf = 0; rf < 2; ++rf)
#pragma unroll
            for (int cf = 0; cf < 2; ++cf) {
                const int col = cf * 16 + lm;
                *(f32x4*)&part[(wv * 32 + col) * 36 + rf * 16 + lq * 4] = acc[rf][cf];
            }
        __syncthreads();

        float gs[4];
#pragma unroll
        for (int g = 0; g < 4; ++g) {
            const int col = g * 8 + jp;
            gs[g] = part[(0 * 32 + col) * 36 + row_l] + part[(1 * 32 + col) * 36 + row_l]
                  + part[(2 * 32 + col) * 36 + row_l] + part[(3 * 32 + col) * 36 + row_l]
                  + bias_r[g];
        }
        const float ft = sigmoidf_(gs[0]);
        const float it = sigmoidf_(gs[1]);
        const float ot = sigmoidf_(gs[2]);
        const float ut = tanhf(gs[3]);
        cst = ft * cst + it * ut;
        const float hv = ot * tanhf(cst);

        // ---- publish h (bypass store), then arrive ----
        const uint32_t hb = (uint32_t)__builtin_bit_cast(uint16_t, (bf16_t)hv);
        const uint32_t nb = __shfl_down(hb, 1);
        if ((lane & 1) == 0) {
            __hip_atomic_store((uint32_t*)(hnext + (size_t)(row0 + row_l) * DLAT + j0 + jp),
                               hb | (nb << 16), __ATOMIC_RELAXED, __HIP_MEMORY_SCOPE_AGENT);
        }
        asm volatile("s_waitcnt vmcnt(0)" ::: "memory");   // h stores at coherence point
        __syncthreads();
        if (tid == 0)
            __hip_atomic_fetch_add(&cnt[(size_t)t * 128 + (blockIdx.x & 7) * 16], 1,
                                   __ATOMIC_RELAXED, __HIP_MEMORY_SCOPE_AGENT);

        // out store off the critical path (plain cached store)
        out[(size_t)t * (BATCH * DLAT) + (size_t)(row0 + row_l) * DLAT + j0 + jp] = hv;

        // ---- overlap: x_{t+1} GEMM into fresh acc while others finish ----
#pragma unroll
        for (int rf = 0; rf < 2; ++rf)
#pragma unroll
            for (int cf = 0; cf < 2; ++cf) acc[rf][cf] = (f32x4){0.f, 0.f, 0.f, 0.f};
        if (t + 1 < T_STEPS) {
            const bf16_t* xt = xb + (size_t)(t + 1) * (BATCH * DIN);
#pragma unroll
            for (int ks = 0; ks < 4; ++ks) {
                const int kx = wv * 128 + ks * 32;
                const bf16x8 a0 = *(const bf16x8*)(xt + (size_t)(row0 + lm) * DIN + kx + lq * 8);
                const bf16x8 a1 = *(const bf16x8*)(xt + (size_t)(row0 + 16 + lm) * DIN + kx + lq * 8);
                const bf16x8 b0 = ldsB(ldsraw, lm,      kx, lq);
                const bf16x8 b1 = ldsB(ldsraw, 16 + lm, kx, lq);
                acc[0][0] = __builtin_amdgcn_mfma_f32_16x16x32_bf16(a0, b0, acc[0][0], 0, 0, 0);
                acc[0][1] = __builtin_amdgcn_mfma_f32_16x16x32_bf16(a0, b1, acc[0][1], 0, 0, 0);
                acc[1][0] = __builtin_amdgcn_mfma_f32_16x16x32_bf16(a1, b0, acc[1][0], 0, 0, 0);
                acc[1][1] = __builtin_amdgcn_mfma_f32_16x16x32_bf16(a1, b1, acc[1][1], 0, 0, 0);
            }
        }
    }
}

extern "C" void kernel_launch(void* const* d_in, const int* in_sizes, int n_in,
                              void* d_out, int out_size, void* d_ws, size_t ws_size,
                              hipStream_t stream) {
    const float* x  = (const float*)d_in[0];
    const float* Wf = (const float*)d_in[1];
    const float* Wi = (const float*)d_in[2];
    const float* Wo = (const float*)d_in[3];
    const float* Wu = (const float*)d_in[4];
    const float* bf = (const float*)d_in[5];
    const float* bi = (const float*)d_in[6];
    const float* bo = (const float*)d_in[7];
    const float* bu = (const float*)d_in[8];
    float* out = (float*)d_out;

    char* ws = (char*)d_ws;
    bf16_t* xb    = (bf16_t*)(ws + XB_OFF);
    bf16_t* hring = (bf16_t*)(ws + HRING_OFF);
    int*    cnt   = (int*)(ws + CNT_OFF);

    // zero h ring + step counters (every launch/replay)
    hipMemsetAsync(ws + HRING_OFF, 0, ZERO_BYTES, stream);

    // convert x -> bf16
    xconv_kernel<<<16384, 256, 0, stream>>>(x, xb);

    hipFuncSetAttribute((const void*)lstm_main,
                        hipFuncAttributeMaxDynamicSharedMemorySize, LDS_BYTES);

    lstm_main<<<NWG, 256, LDS_BYTES, stream>>>(Wf, Wi, Wo, Wu, bf, bi, bo, bu,
                                               xb, hring, cnt, out);
}

// Round 6
// 2498.149 us; speedup vs baseline: 2.7941x; 1.3280x over previous
//
#include <hip/hip_runtime.h>
#include <hip/hip_bf16.h>
#include <stdint.h>

#define T_STEPS 512
#define BATCH   64
#define DIN     512
#define DLAT    1024
#define NWG     256          // 128 col-groups x 2 row-halves = all 256 CUs

typedef __bf16 bf16_t;
typedef __bf16 bf16x4 __attribute__((ext_vector_type(4)));
typedef __bf16 bf16x8 __attribute__((ext_vector_type(8)));
typedef float  f32x4  __attribute__((ext_vector_type(4)));

// ---- workspace layout (bytes) ----
#define XB_OFF    0u                        // bf16 x [512][64][512] = 33,554,432
#define HRING_OFF 33554432u                 // bf16 h ring [2][64][1024] = 262,144
#define CNT_OFF   (HRING_OFF + 262144u)     // int cnt[512][8][16] = 262,144
#define ZERO_BYTES (262144u + 262144u)

// ---- LDS layout (bytes) ----
#define WT_OFF_B   0          // [32 cols][1536 k] bf16, XOR-swizzled = 98,304
#define PART_OFF_B 98304      // f32 [4][32][36] = 18,432
#define PUB_OFF_B  116736     // bf16 [32 rows][8 cols] = 512
#define LDS_BYTES  117248     // forces 1 WG/CU

__global__ void xconv_kernel(const float* __restrict__ x, bf16_t* __restrict__ xb) {
    size_t i = ((size_t)blockIdx.x * 256 + threadIdx.x) * 4;
    const float4 v = *(const float4*)(x + i);
    bf16x4 o;
    o[0] = (bf16_t)v.x; o[1] = (bf16_t)v.y; o[2] = (bf16_t)v.z; o[3] = (bf16_t)v.w;
    *(bf16x4*)(xb + i) = o;
}

__device__ __forceinline__ float sigmoidf_(float v) { return 1.f / (1.f + __expf(-v)); }

// weight B-fragment from LDS (layout verified R2/R4): lane holds
// W[k = kabs + lq*8 + e][col], byte addr col*3072 + k*2 (^ (col&7)<<4)
__device__ __forceinline__ bf16x8 ldsB(const char* lds, int col, int kabs, int lq) {
    const uint32_t off = (uint32_t)(col * 3072 + kabs * 2 + lq * 16)
                       ^ (uint32_t)((col & 7) << 4);
    return *(const bf16x8*)(lds + WT_OFF_B + off);
}

// device-scope (coherent-at-MALL) 16B load, issued WITHOUT wait.
// Caller must s_waitcnt vmcnt(0) + sched_barrier(0) before consuming.
__device__ __forceinline__ bf16x8 ldh16_issue(const bf16_t* p) {
    f32x4 r;
    asm volatile("global_load_dwordx4 %0, %1, off sc1"
                 : "=v"(r) : "v"(p) : "memory");
    return __builtin_bit_cast(bf16x8, r);
}

// device-scope 16B write-through store
__device__ __forceinline__ void sth16(bf16_t* p, bf16x8 v) {
    const f32x4 d = __builtin_bit_cast(f32x4, v);
    asm volatile("global_store_dwordx4 %0, %1, off sc1"
                 :: "v"(p), "v"(d) : "memory");
}

__launch_bounds__(256, 1)
__global__ void lstm_main(const float* __restrict__ Wf, const float* __restrict__ Wi,
                          const float* __restrict__ Wo, const float* __restrict__ Wu,
                          const float* __restrict__ bfp, const float* __restrict__ bip,
                          const float* __restrict__ bop, const float* __restrict__ bup,
                          const bf16_t* __restrict__ xb,
                          bf16_t* __restrict__ hring,
                          int* __restrict__ cnt,
                          float* __restrict__ out) {
    extern __shared__ char ldsraw[];
    float*  part = (float*)(ldsraw + PART_OFF_B);   // [4][32 cols][36 rows]
    bf16_t* pub  = (bf16_t*)(ldsraw + PUB_OFF_B);   // [32 rows][8 cols]

    const int tid  = threadIdx.x;
    const int wv   = tid >> 6;       // wave 0..3 = K-slice
    const int lane = tid & 63;
    const int lm   = lane & 15;
    const int lq   = lane >> 4;
    const int cg   = blockIdx.x >> 1;   // col-group 0..127 -> j cols [cg*8, cg*8+8)
    const int rh   = blockIdx.x & 1;    // row half
    const int j0   = cg * 8;
    const int row0 = rh * 32;

    // ---- one-time: weights -> LDS bf16 [32 cols][1536 k], XOR-swizzled ----
    {
        const float* Wgs[4] = {Wf, Wi, Wo, Wu};
        const int gate = wv;            // wave = gate
        const int kr   = lane >> 1;     // 0..31
        const int jh   = lane & 1;      // 0/1: which float4 of the 8 cols
        const float* basep = Wgs[gate] + j0 + jh * 4;
        for (int i = 0; i < 48; ++i) {
            const int k = kr + i * 32;
            const float4 w4 = *(const float4*)(basep + (size_t)k * DLAT);
#pragma unroll
            for (int e = 0; e < 4; ++e) {
                const int c = gate * 8 + jh * 4 + e;
                const uint32_t a = (uint32_t)(c * 3072 + k * 2) ^ (uint32_t)((c & 7) << 4);
                *(bf16_t*)(ldsraw + WT_OFF_B + a) = (bf16_t)(&w4.x)[e];
            }
        }
    }

    // elementwise ownership: one (row, j) per thread; tid = row_l*8 + jp
    const int row_l = tid >> 3;          // 0..31 (local row)
    const int jp    = tid & 7;           // 0..7  (j within group)
    const float bias_r[4] = { bfp[j0 + jp], bip[j0 + jp], bop[j0 + jp], bup[j0 + jp] };
    float cst = 0.f;

    __syncthreads();   // weights visible

    f32x4 acc[2][2];
#pragma unroll
    for (int rf = 0; rf < 2; ++rf)
#pragma unroll
        for (int cf = 0; cf < 2; ++cf) acc[rf][cf] = (f32x4){0.f, 0.f, 0.f, 0.f};

    // ---- prologue: x_0 GEMM (wave K-slice [wv*128, +128) of DIN) ----
#pragma unroll
    for (int ks = 0; ks < 4; ++ks) {
        const int kx = wv * 128 + ks * 32;
        const bf16x8 a0 = *(const bf16x8*)(xb + (size_t)(row0 + lm) * DIN + kx + lq * 8);
        const bf16x8 a1 = *(const bf16x8*)(xb + (size_t)(row0 + 16 + lm) * DIN + kx + lq * 8);
        const bf16x8 b0 = ldsB(ldsraw, lm,      kx, lq);
        const bf16x8 b1 = ldsB(ldsraw, 16 + lm, kx, lq);
        acc[0][0] = __builtin_amdgcn_mfma_f32_16x16x32_bf16(a0, b0, acc[0][0], 0, 0, 0);
        acc[0][1] = __builtin_amdgcn_mfma_f32_16x16x32_bf16(a0, b1, acc[0][1], 0, 0, 0);
        acc[1][0] = __builtin_amdgcn_mfma_f32_16x16x32_bf16(a1, b0, acc[1][0], 0, 0, 0);
        acc[1][1] = __builtin_amdgcn_mfma_f32_16x16x32_bf16(a1, b1, acc[1][1], 0, 0, 0);
    }

    for (int t = 0; t < T_STEPS; ++t) {
        const bf16_t* hprev = hring + (size_t)(t & 1) * (BATCH * DLAT);
        bf16_t*       hnext = hring + (size_t)((t + 1) & 1) * (BATCH * DLAT);

        // ---- wait for h_t arrivals (cnt[t-1]); no fences needed: hring is
        // only ever touched with device-scope (sc1) ops ----
        if (t > 0) {
            if (tid == 0) {
                int* cb = cnt + (size_t)(t - 1) * 128;
                int s;
                do {
                    s = 0;
#pragma unroll
                    for (int i = 0; i < 8; ++i)
                        s += __hip_atomic_load(&cb[i * 16], __ATOMIC_RELAXED,
                                               __HIP_MEMORY_SCOPE_AGENT);
                    if (s < NWG) __builtin_amdgcn_s_sleep(1);
                } while (s < NWG);
            }
            __syncthreads();
        }

        // ---- h GEMM: batched issue of 16 coherent 16B loads, then B-frags,
        // then ONE wait, then 32 pure-register MFMAs ----
        {
            const bf16_t* hb0 = hprev + (size_t)(row0 + lm) * DLAT + wv * 256 + lq * 8;
            const bf16_t* hb1 = hb0 + (size_t)16 * DLAT;
            bf16x8 ha0[8], ha1[8];
#pragma unroll
            for (int ks = 0; ks < 8; ++ks) {
                ha0[ks] = ldh16_issue(hb0 + ks * 32);
                ha1[ks] = ldh16_issue(hb1 + ks * 32);
            }
            bf16x8 wb0[8], wb1[8];
#pragma unroll
            for (int ks = 0; ks < 8; ++ks) {
                const int kz = 512 + wv * 256 + ks * 32;
                wb0[ks] = ldsB(ldsraw, lm,      kz, lq);
                wb1[ks] = ldsB(ldsraw, 16 + lm, kz, lq);
            }
            asm volatile("s_waitcnt vmcnt(0)" ::: "memory");
            __builtin_amdgcn_sched_barrier(0);
#pragma unroll
            for (int ks = 0; ks < 8; ++ks) {
                acc[0][0] = __builtin_amdgcn_mfma_f32_16x16x32_bf16(ha0[ks], wb0[ks], acc[0][0], 0, 0, 0);
                acc[0][1] = __builtin_amdgcn_mfma_f32_16x16x32_bf16(ha0[ks], wb1[ks], acc[0][1], 0, 0, 0);
                acc[1][0] = __builtin_amdgcn_mfma_f32_16x16x32_bf16(ha1[ks], wb0[ks], acc[1][0], 0, 0, 0);
                acc[1][1] = __builtin_amdgcn_mfma_f32_16x16x32_bf16(ha1[ks], wb1[ks], acc[1][1], 0, 0, 0);
            }
        }

        // ---- cross-wave K-reduction via LDS ----
#pragma unroll
        for (int rf = 0; rf < 2; ++rf)
#pragma unroll
            for (int cf = 0; cf < 2; ++cf) {
                const int col = cf * 16 + lm;
                *(f32x4*)&part[(wv * 32 + col) * 36 + rf * 16 + lq * 4] = acc[rf][cf];
            }
        __syncthreads();

        float gs[4];
#pragma unroll
        for (int g = 0; g < 4; ++g) {
            const int col = g * 8 + jp;
            gs[g] = part[(0 * 32 + col) * 36 + row_l] + part[(1 * 32 + col) * 36 + row_l]
                  + part[(2 * 32 + col) * 36 + row_l] + part[(3 * 32 + col) * 36 + row_l]
                  + bias_r[g];
        }
        const float ft = sigmoidf_(gs[0]);
        const float it = sigmoidf_(gs[1]);
        const float ot = sigmoidf_(gs[2]);
        const float ut = tanhf(gs[3]);
        cst = ft * cst + it * ut;
        const float hv = ot * tanhf(cst);

        // stage h_t tile in LDS (tid = row_l*8 + jp exactly matches layout)
        pub[tid] = (bf16_t)hv;
        // out store (cached path, off critical chain)
        out[(size_t)t * (BATCH * DLAT) + (size_t)(row0 + row_l) * DLAT + j0 + jp] = hv;
        __syncthreads();     // pub visible + part reads complete

        // ---- publish h: 32 coalesced 16B write-through stores (wave 0) ----
        if (tid < 32) {
            const bf16x8 hrow = *(const bf16x8*)(pub + tid * 8);
            sth16(hnext + (size_t)(row0 + tid) * DLAT + j0, hrow);
        }
        if (wv == 0) {
            asm volatile("s_waitcnt vmcnt(0)" ::: "memory");   // stores at MALL
        }
        if (tid == 0)
            __hip_atomic_fetch_add(&cnt[(size_t)t * 128 + (blockIdx.x & 7) * 16], 1,
                                   __ATOMIC_RELAXED, __HIP_MEMORY_SCOPE_AGENT);

        // ---- overlap: x_{t+1} GEMM into fresh acc while others finish ----
#pragma unroll
        for (int rf = 0; rf < 2; ++rf)
#pragma unroll
            for (int cf = 0; cf < 2; ++cf) acc[rf][cf] = (f32x4){0.f, 0.f, 0.f, 0.f};
        if (t + 1 < T_STEPS) {
            const bf16_t* xt = xb + (size_t)(t + 1) * (BATCH * DIN);
#pragma unroll
            for (int ks = 0; ks < 4; ++ks) {
                const int kx = wv * 128 + ks * 32;
                const bf16x8 a0 = *(const bf16x8*)(xt + (size_t)(row0 + lm) * DIN + kx + lq * 8);
                const bf16x8 a1 = *(const bf16x8*)(xt + (size_t)(row0 + 16 + lm) * DIN + kx + lq * 8);
                const bf16x8 b0 = ldsB(ldsraw, lm,      kx, lq);
                const bf16x8 b1 = ldsB(ldsraw, 16 + lm, kx, lq);
                acc[0][0] = __builtin_amdgcn_mfma_f32_16x16x32_bf16(a0, b0, acc[0][0], 0, 0, 0);
                acc[0][1] = __builtin_amdgcn_mfma_f32_16x16x32_bf16(a0, b1, acc[0][1], 0, 0, 0);
                acc[1][0] = __builtin_amdgcn_mfma_f32_16x16x32_bf16(a1, b0, acc[1][0], 0, 0, 0);
                acc[1][1] = __builtin_amdgcn_mfma_f32_16x16x32_bf16(a1, b1, acc[1][1], 0, 0, 0);
            }
        }
    }
}

extern "C" void kernel_launch(void* const* d_in, const int* in_sizes, int n_in,
                              void* d_out, int out_size, void* d_ws, size_t ws_size,
                              hipStream_t stream) {
    const float* x  = (const float*)d_in[0];
    const float* Wf = (const float*)d_in[1];
    const float* Wi = (const float*)d_in[2];
    const float* Wo = (const float*)d_in[3];
    const float* Wu = (const float*)d_in[4];
    const float* bf = (const float*)d_in[5];
    const float* bi = (const float*)d_in[6];
    const float* bo = (const float*)d_in[7];
    const float* bu = (const float*)d_in[8];
    float* out = (float*)d_out;

    char* ws = (char*)d_ws;
    bf16_t* xb    = (bf16_t*)(ws + XB_OFF);
    bf16_t* hring = (bf16_t*)(ws + HRING_OFF);
    int*    cnt   = (int*)(ws + CNT_OFF);

    // zero h ring + step counters (every launch/replay)
    (void)hipMemsetAsync(ws + HRING_OFF, 0, ZERO_BYTES, stream);

    // convert x -> bf16
    xconv_kernel<<<16384, 256, 0, stream>>>(x, xb);

    (void)hipFuncSetAttribute((const void*)lstm_main,
                              hipFuncAttributeMaxDynamicSharedMemorySize, LDS_BYTES);

    lstm_main<<<NWG, 256, LDS_BYTES, stream>>>(Wf, Wi, Wo, Wu, bf, bi, bo, bu,
                                               xb, hring, cnt, out);
}